// Round 1
// baseline (42.227 us; speedup 1.0000x reference)
//
#include <hip/hip_runtime.h>

#define B   4
#define N   1024
#define F   128
#define HID 64
#define EMB 32
#define NIC 32          // i-chunks
#define IC  (N/NIC)     // 32 rows of i per chunk
#define JB  256         // j per block

// ---------------- Kernel 1: per-row MLP -> e, a_i, a_j ----------------
// One wave per row r in [0, B*N). 4 waves / block.
__global__ __launch_bounds__(256) void k1_embed(
    const float* __restrict__ x,  const float* __restrict__ W1, const float* __restrict__ b1,
    const float* __restrict__ W2, const float* __restrict__ b2,
    const float* __restrict__ Wa1,
    float* __restrict__ e, float* __restrict__ ai, float* __restrict__ aj)
{
    __shared__ float sh_x[4][F];
    __shared__ float sh_h[4][HID];
    __shared__ float sh_e[4][EMB];
    const int tid  = threadIdx.x;
    const int w    = tid >> 6;
    const int lane = tid & 63;
    const int r    = blockIdx.x * 4 + w;

    // stage x row into LDS (broadcast source for the dot products)
    sh_x[w][lane]      = x[(size_t)r * F + lane];
    sh_x[w][lane + 64] = x[(size_t)r * F + 64 + lane];
    __syncthreads();

    // h[lane] = relu(x_row . W1[:,lane] + b1[lane])
    float acc = b1[lane];
    #pragma unroll 8
    for (int k = 0; k < F; ++k)
        acc = fmaf(sh_x[w][k], W1[k * HID + lane], acc);
    sh_h[w][lane] = fmaxf(acc, 0.f);
    __syncthreads();

    // e[d] = h . W2[:,d] + b2[d]   (all lanes compute, lanes<32 write)
    const int d = lane & 31;
    float ev = b2[d];
    #pragma unroll 8
    for (int k = 0; k < HID; ++k)
        ev = fmaf(sh_h[w][k], W2[k * EMB + d], ev);
    if (lane < EMB) {
        sh_e[w][d] = ev;
        e[(size_t)r * EMB + d] = ev;
    }
    __syncthreads();

    // lanes 0..31 -> a_i[d] = e . Wa1[:EMB][:,d];  lanes 32..63 -> a_j via Wa1[EMB:]
    const float* Wp = Wa1 + (lane < 32 ? 0 : EMB * EMB);
    float av = 0.f;
    #pragma unroll 8
    for (int k = 0; k < EMB; ++k)
        av = fmaf(sh_e[w][k], Wp[k * EMB + d], av);
    if (lane < 32) ai[(size_t)r * EMB + d] = av;
    else           aj[(size_t)r * EMB + d] = av;
}

// ---------------- Kernel 2: s_part[b,ic,j] = sum_{i in chunk} att[b,i,j] ----
// block = 256 threads (one j each); grid = (NIC, B*N/JB)
__global__ __launch_bounds__(256) void k2_att(
    const float* __restrict__ ai, const float* __restrict__ aj,
    const float* __restrict__ ba1, const float* __restrict__ Wa2,
    const float* __restrict__ ba2, const float* __restrict__ adj,
    float* __restrict__ s_part)
{
    const int ic   = blockIdx.x;
    const int b    = blockIdx.y >> 2;
    const int jblk = blockIdx.y & 3;
    const int tid  = threadIdx.x;
    const int j    = jblk * JB + tid;

    __shared__ float4 sh_ai[IC][EMB / 4];   // 32 rows x 8 float4 = 4 KiB
    {   // cooperative stage: 256 float4 = exactly one per thread
        const int row = tid >> 3, c4 = tid & 7;
        const float4* src = (const float4*)(ai + ((size_t)b * N + ic * IC + row) * EMB);
        sh_ai[row][c4] = src[c4];
    }

    // per-thread a_j + ba1 in registers
    float ajb[EMB];
    {
        const float* ap = aj + ((size_t)b * N + j) * EMB;
        #pragma unroll
        for (int d2 = 0; d2 < EMB; ++d2) ajb[d2] = ap[d2] + ba1[d2];
    }
    float w2r[EMB];
    #pragma unroll
    for (int d2 = 0; d2 < EMB; ++d2) w2r[d2] = Wa2[d2];
    const float bb = ba2[0];
    __syncthreads();

    float ssum = 0.f;
    const float* adjp = adj + (size_t)(ic * IC) * N + j;
    for (int i = 0; i < IC; ++i) {
        const float4* arow = sh_ai[i];
        float dot = bb;
        #pragma unroll
        for (int q = 0; q < EMB / 4; ++q) {
            const float4 a4 = arow[q];
            dot = fmaf(fmaxf(a4.x + ajb[4 * q + 0], 0.f), w2r[4 * q + 0], dot);
            dot = fmaf(fmaxf(a4.y + ajb[4 * q + 1], 0.f), w2r[4 * q + 1], dot);
            dot = fmaf(fmaxf(a4.z + ajb[4 * q + 2], 0.f), w2r[4 * q + 2], dot);
            dot = fmaf(fmaxf(a4.w + ajb[4 * q + 3], 0.f), w2r[4 * q + 3], dot);
        }
        const float sg = 1.f / (1.f + __expf(-dot));   // sigmoid
        ssum = fmaf(sg, adjp[(size_t)i * N], ssum);    // * adj[i_global, j]
    }
    s_part[((size_t)b * NIC + ic) * N + j] = ssum;
}

// ---------------- Kernel 3: out[b,d] = (1/N) * sum_j s[b,j] * e[b,j,d] ------
__global__ __launch_bounds__(256) void k3_out(
    const float* __restrict__ s_part, const float* __restrict__ e,
    float* __restrict__ out)
{
    const int b   = blockIdx.x;
    const int tid = threadIdx.x;
    float acc[EMB];
    #pragma unroll
    for (int d = 0; d < EMB; ++d) acc[d] = 0.f;

    for (int j = tid; j < N; j += 256) {
        float ssum = 0.f;
        #pragma unroll 8
        for (int ic = 0; ic < NIC; ++ic)
            ssum += s_part[((size_t)b * NIC + ic) * N + j];
        const float* ep = e + ((size_t)b * N + j) * EMB;
        #pragma unroll
        for (int d = 0; d < EMB; ++d) acc[d] = fmaf(ssum, ep[d], acc[d]);
    }

    __shared__ float red[256][EMB + 1];
    #pragma unroll
    for (int d = 0; d < EMB; ++d) red[tid][d] = acc[d];
    __syncthreads();
    if (tid < EMB) {
        float s = 0.f;
        for (int t = 0; t < 256; ++t) s += red[t][tid];
        out[b * EMB + tid] = s * (1.0f / N);
    }
}

// ---------------------------------------------------------------------------
extern "C" void kernel_launch(void* const* d_in, const int* in_sizes, int n_in,
                              void* d_out, int out_size, void* d_ws, size_t ws_size,
                              hipStream_t stream) {
    const float* x    = (const float*)d_in[0];
    const float* adj  = (const float*)d_in[1];
    const float* W1   = (const float*)d_in[2];
    const float* b1   = (const float*)d_in[3];
    const float* W2   = (const float*)d_in[4];
    const float* b2   = (const float*)d_in[5];
    const float* Wa1  = (const float*)d_in[6];
    const float* ba1  = (const float*)d_in[7];
    const float* Wa2  = (const float*)d_in[8];
    const float* ba2  = (const float*)d_in[9];
    float* out = (float*)d_out;

    float* ws = (float*)d_ws;
    float* e      = ws;                 // B*N*EMB = 131072
    float* ai     = ws + 131072;        // 131072
    float* aj     = ws + 262144;        // 131072
    float* s_part = ws + 393216;        // B*NIC*N = 131072

    k1_embed<<<(B * N) / 4, 256, 0, stream>>>(x, W1, b1, W2, b2, Wa1, e, ai, aj);
    k2_att<<<dim3(NIC, B * (N / JB)), 256, 0, stream>>>(ai, aj, ba1, Wa2, ba2, adj, s_part);
    k3_out<<<B, 256, 0, stream>>>(s_part, e, out);
}